// Round 2
// baseline (237.516 us; speedup 1.0000x reference)
//
#include <hip/hip_runtime.h>
#include <hip/hip_bf16.h>

// Problem constants
#define BB    8
#define NNODE 128
#define CIN   512
#define HH    8
#define DDIM  64
#define HD    512   // H*D

typedef float f32x4 __attribute__((ext_vector_type(4)));
typedef short bf16x8 __attribute__((ext_vector_type(8)));

static __device__ __forceinline__ unsigned short f2bf(float f) {
    unsigned int x = __float_as_uint(f);
    x = x + 0x7FFFu + ((x >> 16) & 1u);
    return (unsigned short)(x >> 16);
}

static __device__ __forceinline__ bf16x8 pack8(f32x4 a, f32x4 b) {
    bf16x8 r;
    r[0] = (short)f2bf(a[0]); r[1] = (short)f2bf(a[1]);
    r[2] = (short)f2bf(a[2]); r[3] = (short)f2bf(a[3]);
    r[4] = (short)f2bf(b[0]); r[5] = (short)f2bf(b[1]);
    r[6] = (short)f2bf(b[2]); r[7] = (short)f2bf(b[3]);
    return r;
}

// ---------------------------------------------------------------------------
// Kernel 1: tiled transpose+convert W [c][hd] f32 -> WT [m][hd][c] bf16.
// grid (8 c-tiles, 8 hd-tiles, 4 matrices), block 256.
// ---------------------------------------------------------------------------
__global__ __launch_bounds__(256) void k_wt(
    const float* __restrict__ We, const float* __restrict__ Wq,
    const float* __restrict__ Wk, const float* __restrict__ Wv,
    unsigned short* __restrict__ WT)
{
    __shared__ unsigned short tile[64][72];
    const int cb = blockIdx.x;          // c tile
    const int hb = blockIdx.y;          // hd tile
    const int m  = blockIdx.z;          // 0=We,1=Wq,2=Wk,3=Wv
    const float* W = (m == 0) ? We : (m == 1) ? Wq : (m == 2) ? Wk : Wv;
    const int t = threadIdx.x;

#pragma unroll
    for (int it = 0; it < 4; ++it) {
        int row = it * 16 + (t >> 4);       // c within tile
        int col = (t & 15) * 4;             // hd within tile
        f32x4 v = *reinterpret_cast<const f32x4*>(W + (size_t)(cb * 64 + row) * HD + hb * 64 + col);
        tile[row][col + 0] = f2bf(v[0]);
        tile[row][col + 1] = f2bf(v[1]);
        tile[row][col + 2] = f2bf(v[2]);
        tile[row][col + 3] = f2bf(v[3]);
    }
    __syncthreads();

#pragma unroll
    for (int it = 0; it < 4; ++it) {
        int hd = it * 16 + (t >> 4);        // hd within tile
        int c  = (t & 15) * 4;              // c within tile
        unsigned long long pk =
            (unsigned long long)(unsigned short)tile[c + 0][hd] |
            ((unsigned long long)(unsigned short)tile[c + 1][hd] << 16) |
            ((unsigned long long)(unsigned short)tile[c + 2][hd] << 32) |
            ((unsigned long long)(unsigned short)tile[c + 3][hd] << 48);
        *reinterpret_cast<unsigned long long*>(
            &WT[((size_t)m * HD + hb * 64 + hd) * CIN + cb * 64 + c]) = pk;
    }
}

// ---------------------------------------------------------------------------
// Kernel 2: QKV projections via bf16 MFMA (unchanged from round 1).
// ---------------------------------------------------------------------------
__global__ __launch_bounds__(256) void k_qkv(
    const float* __restrict__ hin,
    const unsigned short* __restrict__ WT,
    const float* __restrict__ bq, const float* __restrict__ bk, const float* __restrict__ bv,
    float* __restrict__ Qo, float* __restrict__ Ko, float* __restrict__ Vo)
{
    __shared__ unsigned short hs[64][520];
    const int rt = blockIdx.x;
    const int ct = blockIdx.y;
    const int m  = blockIdx.z;
    const int t  = threadIdx.x;
    const int w  = t >> 6;
    const int l  = t & 63;
    const int g  = l >> 4;
    const int c15 = l & 15;
    const float* bias = (m == 0) ? bq : (m == 1) ? bk : bv;
    float* Out = (m == 0) ? Qo : (m == 1) ? Ko : Vo;
    const unsigned short* Wm = WT + (size_t)(m + 1) * HD * CIN;
    const int rowbase = rt * 64;
    const int colbase = ct * 64;

#pragma unroll
    for (int q = 0; q < 32; ++q) {
        int f = q * 1024 + t * 4;
        int row = f >> 9;
        int c = f & 511;
        f32x4 hv = *reinterpret_cast<const f32x4*>(hin + (size_t)(rowbase + row) * CIN + c);
        unsigned long long pk =
            (unsigned long long)f2bf(hv[0]) |
            ((unsigned long long)f2bf(hv[1]) << 16) |
            ((unsigned long long)f2bf(hv[2]) << 32) |
            ((unsigned long long)f2bf(hv[3]) << 48);
        *reinterpret_cast<unsigned long long*>(&hs[row][c]) = pk;
    }
    __syncthreads();

    f32x4 acc[4];
#pragma unroll
    for (int nf = 0; nf < 4; ++nf) acc[nf] = (f32x4){0.f, 0.f, 0.f, 0.f};

#pragma unroll
    for (int kt = 0; kt < 16; ++kt) {
        bf16x8 afr = *reinterpret_cast<const bf16x8*>(&hs[w * 16 + c15][kt * 32 + g * 8]);
#pragma unroll
        for (int nf = 0; nf < 4; ++nf) {
            const unsigned short* wp = Wm + (size_t)(colbase + nf * 16 + c15) * CIN + kt * 32 + g * 8;
            bf16x8 bfr = *reinterpret_cast<const bf16x8*>(wp);
            acc[nf] = __builtin_amdgcn_mfma_f32_16x16x32_bf16(afr, bfr, acc[nf], 0, 0, 0);
        }
    }

    const float scale = (m == 1) ? 0.125f : 1.0f;
#pragma unroll
    for (int nf = 0; nf < 4; ++nf) {
        int col = colbase + nf * 16 + c15;
        float bv_ = bias[col];
#pragma unroll
        for (int r = 0; r < 4; ++r) {
            int row = rowbase + w * 16 + g * 4 + r;
            Out[(size_t)row * HD + col] = (acc[nf][r] + bv_) * scale;
        }
    }
}

// ---------------------------------------------------------------------------
// Kernel 3: main fused kernel, v2.
// One block per (b,i): 1024 threads = 16 waves. Wave w: head h=w>>1,
// j-half jh=w&1 (64 j's). acc = 4 jm x 4 dc x f32x4 = 64 VGPRs -> 16 waves/CU.
// e staged in 8 sub-chunks of 64 columns, double-buffered bf16 LDS.
// ---------------------------------------------------------------------------
__global__ __launch_bounds__(1024, 4) void k_main(
    const float* __restrict__ e, const float* __restrict__ k_RW,
    const unsigned short* __restrict__ WT,   // We slice at offset 0: [hd][c] bf16
    const float* __restrict__ be,
    const float* __restrict__ Qw, const float* __restrict__ Kw, const float* __restrict__ Vw,
    float* __restrict__ out)
{
    __shared__ unsigned short e_s[2][128][72];   // 2 x 128 rows x 64 c (+pad to 72)
    __shared__ float s_lds[8][128];
    __shared__ float po[8][64];
    __shared__ float pd[8][64];

    const int bi = blockIdx.x;        // b*128 + i
    const int b  = bi >> 7;
    const int t  = threadIdx.x;
    const int w  = t >> 6;            // wave 0..15
    const int h  = w >> 1;            // head 0..7
    const int jh = w & 1;             // j-half
    const int l  = t & 63;
    const int g  = l >> 4;
    const int c15 = l & 15;

    const float* ebase = e + (size_t)bi * (NNODE * CIN);

    // staging assignment: thread t loads row=t/8, columns [(t%8)*8, +8)
    const int srow = t >> 3;
    const int sc0  = (t & 7) * 8;
    const float* gsrc = ebase + (size_t)srow * CIN + sc0;

    f32x4 acc[4][4];
#pragma unroll
    for (int jm = 0; jm < 4; ++jm)
#pragma unroll
        for (int dc = 0; dc < 4; ++dc)
            acc[jm][dc] = (f32x4){0.f, 0.f, 0.f, 0.f};

    // WT base for this lane's (h, c15)
    const unsigned short* wt_l = WT + (size_t)(h * 64 + c15) * CIN;

    // prologue: stage sub-chunk 0
    {
        f32x4 st0 = *reinterpret_cast<const f32x4*>(gsrc);
        f32x4 st1 = *reinterpret_cast<const f32x4*>(gsrc + 4);
        *reinterpret_cast<bf16x8*>(&e_s[0][srow][sc0]) = pack8(st0, st1);
    }
    __syncthreads();

    for (int s = 0; s < 8; ++s) {
        const int buf = s & 1;
        f32x4 st0, st1;
        if (s < 7) {
            st0 = *reinterpret_cast<const f32x4*>(gsrc + (s + 1) * 64);
            st1 = *reinterpret_cast<const f32x4*>(gsrc + (s + 1) * 64 + 4);
        }
#pragma unroll
        for (int ktl = 0; ktl < 2; ++ktl) {
            bf16x8 bfr[4];
#pragma unroll
            for (int dc = 0; dc < 4; ++dc) {
                bfr[dc] = *reinterpret_cast<const bf16x8*>(
                    wt_l + (size_t)dc * 16 * CIN + s * 64 + ktl * 32 + g * 8);
            }
#pragma unroll
            for (int jm = 0; jm < 4; ++jm) {
                bf16x8 afr = *reinterpret_cast<const bf16x8*>(
                    &e_s[buf][jh * 64 + jm * 16 + c15][ktl * 32 + g * 8]);
#pragma unroll
                for (int dc = 0; dc < 4; ++dc) {
                    acc[jm][dc] = __builtin_amdgcn_mfma_f32_16x16x32_bf16(afr, bfr[dc], acc[jm][dc], 0, 0, 0);
                }
            }
        }
        if (s < 7) {
            *reinterpret_cast<bf16x8*>(&e_s[buf ^ 1][srow][sc0]) = pack8(st0, st1);
        }
        __syncthreads();
    }

    // ---- epilogue: scores ----
    const float* Kb  = Kw + (size_t)b * NNODE * HD;
    const float* krw = k_RW + (size_t)bi * NNODE;
    float q_l[4], be_l[4];
#pragma unroll
    for (int dc = 0; dc < 4; ++dc) {
        q_l[dc]  = Qw[(size_t)bi * HD + h * 64 + dc * 16 + c15];
        be_l[dc] = be[h * 64 + dc * 16 + c15];
    }

#pragma unroll
    for (int jm = 0; jm < 4; ++jm) {
#pragma unroll
        for (int r = 0; r < 4; ++r) {
            int j = jh * 64 + jm * 16 + g * 4 + r;
            float sacc = 0.f;
#pragma unroll
            for (int dc = 0; dc < 4; ++dc) {
                float ev = acc[jm][dc][r] + be_l[dc];
                float kv = Kb[(size_t)j * HD + h * 64 + dc * 16 + c15];
                sacc += ev * q_l[dc] * kv;
            }
            sacc += __shfl_xor(sacc, 1);
            sacc += __shfl_xor(sacc, 2);
            sacc += __shfl_xor(sacc, 4);
            sacc += __shfl_xor(sacc, 8);
            if (c15 == 0) {
                float sv = fminf(fmaxf(sacc, -5.f), 5.f);
                s_lds[h][j] = __expf(sv) * krw[j];
            }
        }
    }
    __syncthreads();

    // ---- PV + denom, split across wave halves ----
    const float* Vb = Vw + (size_t)b * NNODE * HD;
    const int h2 = w & 7;
    const int j0 = (w < 8) ? 0 : 64;
    float o = 0.f, den = 0.f;
#pragma unroll 4
    for (int jj = 0; jj < 64; ++jj) {
        int j = j0 + jj;
        float sv = s_lds[h2][j];
        o = fmaf(sv, Vb[(size_t)j * HD + h2 * 64 + l], o);
        den += sv;
    }
    if (w >= 8) {
        po[h2][l] = o;
        pd[h2][l] = den;
    }
    __syncthreads();
    if (w < 8) {
        o   += po[h2][l];
        den += pd[h2][l];
        den = fmaxf(den, 1e-6f);
        out[(size_t)bi * HD + h2 * 64 + l] = o / den;
    }
}

// ---------------------------------------------------------------------------
extern "C" void kernel_launch(void* const* d_in, const int* in_sizes, int n_in,
                              void* d_out, int out_size, void* d_ws, size_t ws_size,
                              hipStream_t stream) {
    const float* hin = (const float*)d_in[0];
    const float* e   = (const float*)d_in[1];
    const float* krw = (const float*)d_in[2];
    const float* Wq  = (const float*)d_in[3];
    const float* bq  = (const float*)d_in[4];
    const float* Wk  = (const float*)d_in[5];
    const float* bk  = (const float*)d_in[6];
    const float* We  = (const float*)d_in[7];
    const float* be  = (const float*)d_in[8];
    const float* Wv  = (const float*)d_in[9];
    const float* bv  = (const float*)d_in[10];
    float* out = (float*)d_out;

    char* ws = (char*)d_ws;
    unsigned short* WT = (unsigned short*)ws;                 // 4*512*512 bf16 = 2 MB
    float* Q = (float*)(ws + (2ull << 20));
    float* K = (float*)(ws + (4ull << 20));
    float* V = (float*)(ws + (6ull << 20));

    k_wt<<<dim3(8, 8, 4), dim3(256), 0, stream>>>(We, Wq, Wk, Wv, WT);
    k_qkv<<<dim3(16, 8, 3), dim3(256), 0, stream>>>(hin, WT, bq, bk, bv, Q, K, V);
    k_main<<<dim3(1024), dim3(1024), 0, stream>>>(e, krw, WT, be, Q, K, V, out);
}

// Round 3
// 233.179 us; speedup vs baseline: 1.0186x; 1.0186x over previous
//
#include <hip/hip_runtime.h>
#include <hip/hip_bf16.h>

// Problem constants
#define BB    8
#define NNODE 128
#define CIN   512
#define HH    8
#define DDIM  64
#define HD    512   // H*D

typedef float f32x4 __attribute__((ext_vector_type(4)));
typedef short bf16x8 __attribute__((ext_vector_type(8)));

static __device__ __forceinline__ unsigned short f2bf(float f) {
    unsigned int x = __float_as_uint(f);
    x = x + 0x7FFFu + ((x >> 16) & 1u);
    return (unsigned short)(x >> 16);
}

static __device__ __forceinline__ bf16x8 pack8(f32x4 a, f32x4 b) {
    bf16x8 r;
    r[0] = (short)f2bf(a[0]); r[1] = (short)f2bf(a[1]);
    r[2] = (short)f2bf(a[2]); r[3] = (short)f2bf(a[3]);
    r[4] = (short)f2bf(b[0]); r[5] = (short)f2bf(b[1]);
    r[6] = (short)f2bf(b[2]); r[7] = (short)f2bf(b[3]);
    return r;
}

// ---------------------------------------------------------------------------
// Kernel 1: tiled transpose+convert W [c][hd] f32 -> WT [m][hd][c] bf16.
// ---------------------------------------------------------------------------
__global__ __launch_bounds__(256) void k_wt(
    const float* __restrict__ We, const float* __restrict__ Wq,
    const float* __restrict__ Wk, const float* __restrict__ Wv,
    unsigned short* __restrict__ WT)
{
    __shared__ unsigned short tile[64][72];
    const int cb = blockIdx.x;
    const int hb = blockIdx.y;
    const int m  = blockIdx.z;
    const float* W = (m == 0) ? We : (m == 1) ? Wq : (m == 2) ? Wk : Wv;
    const int t = threadIdx.x;

#pragma unroll
    for (int it = 0; it < 4; ++it) {
        int row = it * 16 + (t >> 4);
        int col = (t & 15) * 4;
        f32x4 v = *reinterpret_cast<const f32x4*>(W + (size_t)(cb * 64 + row) * HD + hb * 64 + col);
        tile[row][col + 0] = f2bf(v[0]);
        tile[row][col + 1] = f2bf(v[1]);
        tile[row][col + 2] = f2bf(v[2]);
        tile[row][col + 3] = f2bf(v[3]);
    }
    __syncthreads();

#pragma unroll
    for (int it = 0; it < 4; ++it) {
        int hd = it * 16 + (t >> 4);
        int c  = (t & 15) * 4;
        unsigned long long pk =
            (unsigned long long)(unsigned short)tile[c + 0][hd] |
            ((unsigned long long)(unsigned short)tile[c + 1][hd] << 16) |
            ((unsigned long long)(unsigned short)tile[c + 2][hd] << 32) |
            ((unsigned long long)(unsigned short)tile[c + 3][hd] << 48);
        *reinterpret_cast<unsigned long long*>(
            &WT[((size_t)m * HD + hb * 64 + hd) * CIN + cb * 64 + c]) = pk;
    }
}

// ---------------------------------------------------------------------------
// Kernel 2: QKV projections via bf16 MFMA.
// ---------------------------------------------------------------------------
__global__ __launch_bounds__(256) void k_qkv(
    const float* __restrict__ hin,
    const unsigned short* __restrict__ WT,
    const float* __restrict__ bq, const float* __restrict__ bk, const float* __restrict__ bv,
    float* __restrict__ Qo, float* __restrict__ Ko, float* __restrict__ Vo)
{
    __shared__ unsigned short hs[64][520];
    const int rt = blockIdx.x;
    const int ct = blockIdx.y;
    const int m  = blockIdx.z;
    const int t  = threadIdx.x;
    const int w  = t >> 6;
    const int l  = t & 63;
    const int g  = l >> 4;
    const int c15 = l & 15;
    const float* bias = (m == 0) ? bq : (m == 1) ? bk : bv;
    float* Out = (m == 0) ? Qo : (m == 1) ? Ko : Vo;
    const unsigned short* Wm = WT + (size_t)(m + 1) * HD * CIN;
    const int rowbase = rt * 64;
    const int colbase = ct * 64;

#pragma unroll
    for (int q = 0; q < 32; ++q) {
        int f = q * 1024 + t * 4;
        int row = f >> 9;
        int c = f & 511;
        f32x4 hv = *reinterpret_cast<const f32x4*>(hin + (size_t)(rowbase + row) * CIN + c);
        unsigned long long pk =
            (unsigned long long)f2bf(hv[0]) |
            ((unsigned long long)f2bf(hv[1]) << 16) |
            ((unsigned long long)f2bf(hv[2]) << 32) |
            ((unsigned long long)f2bf(hv[3]) << 48);
        *reinterpret_cast<unsigned long long*>(&hs[row][c]) = pk;
    }
    __syncthreads();

    f32x4 acc[4];
#pragma unroll
    for (int nf = 0; nf < 4; ++nf) acc[nf] = (f32x4){0.f, 0.f, 0.f, 0.f};

#pragma unroll
    for (int kt = 0; kt < 16; ++kt) {
        bf16x8 afr = *reinterpret_cast<const bf16x8*>(&hs[w * 16 + c15][kt * 32 + g * 8]);
#pragma unroll
        for (int nf = 0; nf < 4; ++nf) {
            const unsigned short* wp = Wm + (size_t)(colbase + nf * 16 + c15) * CIN + kt * 32 + g * 8;
            bf16x8 bfr = *reinterpret_cast<const bf16x8*>(wp);
            acc[nf] = __builtin_amdgcn_mfma_f32_16x16x32_bf16(afr, bfr, acc[nf], 0, 0, 0);
        }
    }

    const float scale = (m == 1) ? 0.125f : 1.0f;
#pragma unroll
    for (int nf = 0; nf < 4; ++nf) {
        int col = colbase + nf * 16 + c15;
        float bv_ = bias[col];
#pragma unroll
        for (int r = 0; r < 4; ++r) {
            int row = rowbase + w * 16 + g * 4 + r;
            Out[(size_t)row * HD + col] = (acc[nf][r] + bv_) * scale;
        }
    }
}

// ---------------------------------------------------------------------------
// Kernel 3: main fused kernel, v3.
// Block = (bi, j-half): 512 threads = 8 waves, wave w = head h, 64 j rows.
// e[bi, j0:j0+64, :] staged in 4 c-chunks of 128, double-buffered, XOR-swizzled
// bf16 LDS (byte ^= (row&7)<<4 per 16B slot). 2 blocks/CU co-resident.
// Writes PV partials (numerator + denominator) to workspace; k_norm combines.
// ---------------------------------------------------------------------------
__global__ __launch_bounds__(512, 4) void k_main(
    const float* __restrict__ e, const float* __restrict__ k_RW,
    const unsigned short* __restrict__ WT,   // We slice at offset 0: [hd][c] bf16
    const float* __restrict__ be,
    const float* __restrict__ Qw, const float* __restrict__ Kw, const float* __restrict__ Vw,
    float* __restrict__ PN, float* __restrict__ PD)
{
    __shared__ unsigned short e_s[2][64 * 128];  // 2 x 16 KB, byte-swizzled
    __shared__ float s_lds[8][64];

    const int bx   = blockIdx.x;
    const int bi   = bx >> 1;         // b*128 + i
    const int half = bx & 1;
    const int b    = bi >> 7;
    const int t    = threadIdx.x;
    const int h    = t >> 6;          // wave id == head
    const int l    = t & 63;
    const int g    = l >> 4;
    const int c15  = l & 15;

    const int j0 = half * 64;
    const float* ebase = e + ((size_t)bi * NNODE + j0) * CIN;

    // staging map: thread t -> row t/8, 16 floats at col (t%8)*16
    const int srow = t >> 3;
    const int scg  = t & 7;
    const float* gsrc = ebase + (size_t)srow * CIN + scg * 16;
    const int xr  = (srow & 7) << 4;
    const int wb0 = srow * 256 + ((scg * 32) ^ xr);
    const int wb1 = srow * 256 + ((scg * 32 + 16) ^ xr);

    f32x4 acc[4][4];
#pragma unroll
    for (int jm = 0; jm < 4; ++jm)
#pragma unroll
        for (int dc = 0; dc < 4; ++dc)
            acc[jm][dc] = (f32x4){0.f, 0.f, 0.f, 0.f};

    const unsigned short* wt_l = WT + (size_t)(h * 64 + c15) * CIN;

    // prologue: stage chunk 0
    {
        f32x4 a0 = *reinterpret_cast<const f32x4*>(gsrc + 0);
        f32x4 a1 = *reinterpret_cast<const f32x4*>(gsrc + 4);
        f32x4 a2 = *reinterpret_cast<const f32x4*>(gsrc + 8);
        f32x4 a3 = *reinterpret_cast<const f32x4*>(gsrc + 12);
        char* base = (char*)&e_s[0][0];
        *reinterpret_cast<bf16x8*>(base + wb0) = pack8(a0, a1);
        *reinterpret_cast<bf16x8*>(base + wb1) = pack8(a2, a3);
    }
    __syncthreads();

    for (int cc = 0; cc < 4; ++cc) {
        const int buf = cc & 1;
        f32x4 a0, a1, a2, a3;
        if (cc < 3) {
            const float* p = gsrc + (cc + 1) * 128;
            a0 = *reinterpret_cast<const f32x4*>(p + 0);
            a1 = *reinterpret_cast<const f32x4*>(p + 4);
            a2 = *reinterpret_cast<const f32x4*>(p + 8);
            a3 = *reinterpret_cast<const f32x4*>(p + 12);
        }
        const char* rbase = (const char*)&e_s[buf][0];
#pragma unroll
        for (int kt = 0; kt < 4; ++kt) {
            bf16x8 bfr[4];
#pragma unroll
            for (int dc = 0; dc < 4; ++dc) {
                bfr[dc] = *reinterpret_cast<const bf16x8*>(
                    wt_l + (size_t)dc * 16 * CIN + cc * 128 + kt * 32 + g * 8);
            }
#pragma unroll
            for (int jm = 0; jm < 4; ++jm) {
                int row = jm * 16 + c15;
                int cb = (kt * 64 + g * 16) ^ ((row & 7) << 4);
                bf16x8 afr = *reinterpret_cast<const bf16x8*>(rbase + row * 256 + cb);
#pragma unroll
                for (int dc = 0; dc < 4; ++dc) {
                    acc[jm][dc] = __builtin_amdgcn_mfma_f32_16x16x32_bf16(afr, bfr[dc], acc[jm][dc], 0, 0, 0);
                }
            }
        }
        if (cc < 3) {
            char* wbase = (char*)&e_s[buf ^ 1][0];
            *reinterpret_cast<bf16x8*>(wbase + wb0) = pack8(a0, a1);
            *reinterpret_cast<bf16x8*>(wbase + wb1) = pack8(a2, a3);
        }
        __syncthreads();
    }

    // ---- epilogue: scores for this wave's head, 64 local j ----
    const float* Kb  = Kw + (size_t)b * NNODE * HD;
    const float* krw = k_RW + (size_t)bi * NNODE + j0;
    float q_l[4], be_l[4];
#pragma unroll
    for (int dc = 0; dc < 4; ++dc) {
        q_l[dc]  = Qw[(size_t)bi * HD + h * 64 + dc * 16 + c15];
        be_l[dc] = be[h * 64 + dc * 16 + c15];
    }

#pragma unroll
    for (int jm = 0; jm < 4; ++jm) {
#pragma unroll
        for (int r = 0; r < 4; ++r) {
            int jl = jm * 16 + g * 4 + r;       // local j within half
            float sacc = 0.f;
#pragma unroll
            for (int dc = 0; dc < 4; ++dc) {
                float ev = acc[jm][dc][r] + be_l[dc];
                float kv = Kb[(size_t)(j0 + jl) * HD + h * 64 + dc * 16 + c15];
                sacc += ev * q_l[dc] * kv;
            }
            sacc += __shfl_xor(sacc, 1);
            sacc += __shfl_xor(sacc, 2);
            sacc += __shfl_xor(sacc, 4);
            sacc += __shfl_xor(sacc, 8);
            if (c15 == 0) {
                float sv = fminf(fmaxf(sacc, -5.f), 5.f);
                s_lds[h][jl] = __expf(sv) * krw[jl];
            }
        }
    }
    __syncthreads();

    // ---- PV partials: wave h, lane = d ----
    const float* Vb = Vw + (size_t)b * NNODE * HD;
    float o = 0.f, den = 0.f;
#pragma unroll 4
    for (int jl = 0; jl < 64; ++jl) {
        float sv = s_lds[h][jl];
        o = fmaf(sv, Vb[(size_t)(j0 + jl) * HD + h * 64 + l], o);
        den += sv;
    }
    PN[((size_t)bx * 8 + h) * 64 + l] = o;
    if (l == 0) PD[(size_t)bx * 8 + h] = den;
}

// ---------------------------------------------------------------------------
// Kernel 4: combine the two j-half partials and normalize.
// ---------------------------------------------------------------------------
__global__ __launch_bounds__(512) void k_norm(
    const float* __restrict__ PN, const float* __restrict__ PD,
    float* __restrict__ out)
{
    const int bi = blockIdx.x;
    const int t  = threadIdx.x;
    const int h  = t >> 6;
    const int d  = t & 63;
    size_t r0 = ((size_t)(bi * 2 + 0) * 8 + h);
    size_t r1 = ((size_t)(bi * 2 + 1) * 8 + h);
    float num = PN[r0 * 64 + d] + PN[r1 * 64 + d];
    float den = fmaxf(PD[r0] + PD[r1], 1e-6f);
    out[(size_t)bi * HD + h * 64 + d] = num / den;
}

// ---------------------------------------------------------------------------
extern "C" void kernel_launch(void* const* d_in, const int* in_sizes, int n_in,
                              void* d_out, int out_size, void* d_ws, size_t ws_size,
                              hipStream_t stream) {
    const float* hin = (const float*)d_in[0];
    const float* e   = (const float*)d_in[1];
    const float* krw = (const float*)d_in[2];
    const float* Wq  = (const float*)d_in[3];
    const float* bq  = (const float*)d_in[4];
    const float* Wk  = (const float*)d_in[5];
    const float* bk  = (const float*)d_in[6];
    const float* We  = (const float*)d_in[7];
    const float* be  = (const float*)d_in[8];
    const float* Wv  = (const float*)d_in[9];
    const float* bv  = (const float*)d_in[10];
    float* out = (float*)d_out;

    char* ws = (char*)d_ws;
    unsigned short* WT = (unsigned short*)ws;                 // 2 MB
    float* Q  = (float*)(ws + (2ull << 20));                  // 2 MB
    float* K  = (float*)(ws + (4ull << 20));                  // 2 MB
    float* V  = (float*)(ws + (6ull << 20));                  // 2 MB
    float* PN = (float*)(ws + (8ull << 20));                  // 2048*8*64*4 = 4 MB
    float* PD = (float*)(ws + (12ull << 20));                 // 64 KB

    k_wt<<<dim3(8, 8, 4), dim3(256), 0, stream>>>(We, Wq, Wk, Wv, WT);
    k_qkv<<<dim3(16, 8, 3), dim3(256), 0, stream>>>(hin, WT, bq, bk, bv, Q, K, V);
    k_main<<<dim3(2048), dim3(512), 0, stream>>>(e, krw, WT, be, Q, K, V, PN, PD);
    k_norm<<<dim3(1024), dim3(512), 0, stream>>>(PN, PD, out);
}

// Round 4
// 179.648 us; speedup vs baseline: 1.3221x; 1.2980x over previous
//
#include <hip/hip_runtime.h>
#include <hip/hip_bf16.h>

// Problem constants
#define BB    8
#define NNODE 128
#define CIN   512
#define HH    8
#define DDIM  64
#define HD    512   // H*D

typedef float f32x4 __attribute__((ext_vector_type(4)));
typedef short bf16x8 __attribute__((ext_vector_type(8)));

static __device__ __forceinline__ unsigned short f2bf(float f) {
    unsigned int x = __float_as_uint(f);
    x = x + 0x7FFFu + ((x >> 16) & 1u);
    return (unsigned short)(x >> 16);
}

static __device__ __forceinline__ bf16x8 pack8(f32x4 a, f32x4 b) {
    bf16x8 r;
    r[0] = (short)f2bf(a[0]); r[1] = (short)f2bf(a[1]);
    r[2] = (short)f2bf(a[2]); r[3] = (short)f2bf(a[3]);
    r[4] = (short)f2bf(b[0]); r[5] = (short)f2bf(b[1]);
    r[6] = (short)f2bf(b[2]); r[7] = (short)f2bf(b[3]);
    return r;
}

// ---------------------------------------------------------------------------
// Kernel 1: tiled transpose+convert Wq/Wk/Wv [c][hd] f32 -> WT [m][hd][c] bf16
// (m slice 1..3; slice 0 unused now). For k_qkv.
// ---------------------------------------------------------------------------
__global__ __launch_bounds__(256) void k_wt(
    const float* __restrict__ Wq, const float* __restrict__ Wk,
    const float* __restrict__ Wv,
    unsigned short* __restrict__ WT)
{
    __shared__ unsigned short tile[64][72];
    const int cb = blockIdx.x;
    const int hb = blockIdx.y;
    const int m  = blockIdx.z;          // 0=Wq,1=Wk,2=Wv
    const float* W = (m == 0) ? Wq : (m == 1) ? Wk : Wv;
    const int t = threadIdx.x;

#pragma unroll
    for (int it = 0; it < 4; ++it) {
        int row = it * 16 + (t >> 4);
        int col = (t & 15) * 4;
        f32x4 v = *reinterpret_cast<const f32x4*>(W + (size_t)(cb * 64 + row) * HD + hb * 64 + col);
        tile[row][col + 0] = f2bf(v[0]);
        tile[row][col + 1] = f2bf(v[1]);
        tile[row][col + 2] = f2bf(v[2]);
        tile[row][col + 3] = f2bf(v[3]);
    }
    __syncthreads();

#pragma unroll
    for (int it = 0; it < 4; ++it) {
        int hd = it * 16 + (t >> 4);
        int c  = (t & 15) * 4;
        unsigned long long pk =
            (unsigned long long)(unsigned short)tile[c + 0][hd] |
            ((unsigned long long)(unsigned short)tile[c + 1][hd] << 16) |
            ((unsigned long long)(unsigned short)tile[c + 2][hd] << 32) |
            ((unsigned long long)(unsigned short)tile[c + 3][hd] << 48);
        *reinterpret_cast<unsigned long long*>(
            &WT[((size_t)(m + 1) * HD + hb * 64 + hd) * CIN + cb * 64 + c]) = pk;
    }
}

// ---------------------------------------------------------------------------
// Kernel 1b: We -> WT2 in MFMA-fragment-linear order.
// WT2 element layout: [h][cc][kt][dc][lane l][i0..7], 16B per lane slot.
// Value = bf16(We[cc*128 + kt*32 + (l>>4)*8 + i][h*64 + dc*16 + (l&15)]).
// Each bfr load in k_main becomes one coalesced 1KB wave read.
// ---------------------------------------------------------------------------
__global__ __launch_bounds__(256) void k_wt2(
    const float* __restrict__ We, unsigned short* __restrict__ WT2)
{
    const int h  = blockIdx.x;          // 0..7
    const int cc = blockIdx.y;          // 0..3
    const int t  = threadIdx.x;
#pragma unroll
    for (int it = 0; it < 4; ++it) {
        int s  = it * 256 + t;          // 0..1023 = (kt,dc,l)
        int kt = s >> 8;
        int dc = (s >> 6) & 3;
        int l  = s & 63;
        int c0 = cc * 128 + kt * 32 + (l >> 4) * 8;
        int hd = h * 64 + dc * 16 + (l & 15);
        unsigned long long pk0 = 0, pk1 = 0;
#pragma unroll
        for (int i = 0; i < 4; ++i)
            pk0 |= (unsigned long long)f2bf(We[(size_t)(c0 + i) * HD + hd]) << (16 * i);
#pragma unroll
        for (int i = 0; i < 4; ++i)
            pk1 |= (unsigned long long)f2bf(We[(size_t)(c0 + 4 + i) * HD + hd]) << (16 * i);
        size_t off = ((((size_t)h * 4 + cc) * 4 + kt) * 4 + dc) * 512 + l * 8;
        *reinterpret_cast<unsigned long long*>(&WT2[off])     = pk0;
        *reinterpret_cast<unsigned long long*>(&WT2[off + 4]) = pk1;
    }
}

// ---------------------------------------------------------------------------
// Kernel 2: QKV projections via bf16 MFMA (unchanged).
// ---------------------------------------------------------------------------
__global__ __launch_bounds__(256) void k_qkv(
    const float* __restrict__ hin,
    const unsigned short* __restrict__ WT,
    const float* __restrict__ bq, const float* __restrict__ bk, const float* __restrict__ bv,
    float* __restrict__ Qo, float* __restrict__ Ko, float* __restrict__ Vo)
{
    __shared__ unsigned short hs[64][520];
    const int rt = blockIdx.x;
    const int ct = blockIdx.y;
    const int m  = blockIdx.z;
    const int t  = threadIdx.x;
    const int w  = t >> 6;
    const int l  = t & 63;
    const int g  = l >> 4;
    const int c15 = l & 15;
    const float* bias = (m == 0) ? bq : (m == 1) ? bk : bv;
    float* Out = (m == 0) ? Qo : (m == 1) ? Ko : Vo;
    const unsigned short* Wm = WT + (size_t)(m + 1) * HD * CIN;
    const int rowbase = rt * 64;
    const int colbase = ct * 64;

#pragma unroll
    for (int q = 0; q < 32; ++q) {
        int f = q * 1024 + t * 4;
        int row = f >> 9;
        int c = f & 511;
        f32x4 hv = *reinterpret_cast<const f32x4*>(hin + (size_t)(rowbase + row) * CIN + c);
        unsigned long long pk =
            (unsigned long long)f2bf(hv[0]) |
            ((unsigned long long)f2bf(hv[1]) << 16) |
            ((unsigned long long)f2bf(hv[2]) << 32) |
            ((unsigned long long)f2bf(hv[3]) << 48);
        *reinterpret_cast<unsigned long long*>(&hs[row][c]) = pk;
    }
    __syncthreads();

    f32x4 acc[4];
#pragma unroll
    for (int nf = 0; nf < 4; ++nf) acc[nf] = (f32x4){0.f, 0.f, 0.f, 0.f};

#pragma unroll
    for (int kt = 0; kt < 16; ++kt) {
        bf16x8 afr = *reinterpret_cast<const bf16x8*>(&hs[w * 16 + c15][kt * 32 + g * 8]);
#pragma unroll
        for (int nf = 0; nf < 4; ++nf) {
            const unsigned short* wp = Wm + (size_t)(colbase + nf * 16 + c15) * CIN + kt * 32 + g * 8;
            bf16x8 bfr = *reinterpret_cast<const bf16x8*>(wp);
            acc[nf] = __builtin_amdgcn_mfma_f32_16x16x32_bf16(afr, bfr, acc[nf], 0, 0, 0);
        }
    }

    const float scale = (m == 1) ? 0.125f : 1.0f;
#pragma unroll
    for (int nf = 0; nf < 4; ++nf) {
        int col = colbase + nf * 16 + c15;
        float bv_ = bias[col];
#pragma unroll
        for (int r = 0; r < 4; ++r) {
            int row = rowbase + w * 16 + g * 4 + r;
            Out[(size_t)row * HD + col] = (acc[nf][r] + bv_) * scale;
        }
    }
}

// ---------------------------------------------------------------------------
// Kernel 3: main fused kernel, v4 = r3 + fragment-linear WT2 B-loads
// (coalesced 1KB wave-loads, kt-pipelined) instead of 16-line gathers.
// Everything else identical to round 3.
// ---------------------------------------------------------------------------
__global__ __launch_bounds__(512, 4) void k_main(
    const float* __restrict__ e, const float* __restrict__ k_RW,
    const unsigned short* __restrict__ WT2,
    const float* __restrict__ be,
    const float* __restrict__ Qw, const float* __restrict__ Kw, const float* __restrict__ Vw,
    float* __restrict__ PN, float* __restrict__ PD)
{
    __shared__ unsigned short e_s[2][64 * 128];  // 2 x 16 KB, byte-swizzled
    __shared__ float s_lds[8][64];

    const int bx   = blockIdx.x;
    const int bi   = bx >> 1;         // b*128 + i
    const int half = bx & 1;
    const int b    = bi >> 7;
    const int t    = threadIdx.x;
    const int h    = t >> 6;          // wave id == head
    const int l    = t & 63;
    const int g    = l >> 4;
    const int c15  = l & 15;

    const int j0 = half * 64;
    const float* ebase = e + ((size_t)bi * NNODE + j0) * CIN;

    // staging map: thread t -> row t/8, 16 floats at col (t%8)*16
    const int srow = t >> 3;
    const int scg  = t & 7;
    const float* gsrc = ebase + (size_t)srow * CIN + scg * 16;
    const int xr  = (srow & 7) << 4;
    const int wb0 = srow * 256 + ((scg * 32) ^ xr);
    const int wb1 = srow * 256 + ((scg * 32 + 16) ^ xr);

    f32x4 acc[4][4];
#pragma unroll
    for (int jm = 0; jm < 4; ++jm)
#pragma unroll
        for (int dc = 0; dc < 4; ++dc)
            acc[jm][dc] = (f32x4){0.f, 0.f, 0.f, 0.f};

    // lane-fixed WT2 pointer: per (cc,kt,dc) a coalesced 16B slot at l*8
    const unsigned short* w2h = WT2 + (size_t)h * 32768 + l * 8;

    // prologue: stage chunk 0
    {
        f32x4 a0 = *reinterpret_cast<const f32x4*>(gsrc + 0);
        f32x4 a1 = *reinterpret_cast<const f32x4*>(gsrc + 4);
        f32x4 a2 = *reinterpret_cast<const f32x4*>(gsrc + 8);
        f32x4 a3 = *reinterpret_cast<const f32x4*>(gsrc + 12);
        char* base = (char*)&e_s[0][0];
        *reinterpret_cast<bf16x8*>(base + wb0) = pack8(a0, a1);
        *reinterpret_cast<bf16x8*>(base + wb1) = pack8(a2, a3);
    }
    __syncthreads();

    for (int cc = 0; cc < 4; ++cc) {
        const int buf = cc & 1;
        f32x4 a0, a1, a2, a3;
        if (cc < 3) {
            const float* p = gsrc + (cc + 1) * 128;
            a0 = *reinterpret_cast<const f32x4*>(p + 0);
            a1 = *reinterpret_cast<const f32x4*>(p + 4);
            a2 = *reinterpret_cast<const f32x4*>(p + 8);
            a3 = *reinterpret_cast<const f32x4*>(p + 12);
        }
        const char* rbase = (const char*)&e_s[buf][0];
        const unsigned short* bptr = w2h + cc * 8192;

        // kt-pipelined B fragments: coalesced 1KB wave-loads from WT2
        bf16x8 bcur[4], bnxt[4];
#pragma unroll
        for (int dc = 0; dc < 4; ++dc)
            bcur[dc] = *reinterpret_cast<const bf16x8*>(bptr + dc * 512);
#pragma unroll
        for (int kt = 0; kt < 4; ++kt) {
            if (kt < 3) {
#pragma unroll
                for (int dc = 0; dc < 4; ++dc)
                    bnxt[dc] = *reinterpret_cast<const bf16x8*>(bptr + (kt + 1) * 2048 + dc * 512);
            }
#pragma unroll
            for (int jm = 0; jm < 4; ++jm) {
                int row = jm * 16 + c15;
                int cb = (kt * 64 + g * 16) ^ ((row & 7) << 4);
                bf16x8 afr = *reinterpret_cast<const bf16x8*>(rbase + row * 256 + cb);
#pragma unroll
                for (int dc = 0; dc < 4; ++dc) {
                    acc[jm][dc] = __builtin_amdgcn_mfma_f32_16x16x32_bf16(afr, bcur[dc], acc[jm][dc], 0, 0, 0);
                }
            }
#pragma unroll
            for (int dc = 0; dc < 4; ++dc) bcur[dc] = bnxt[dc];
        }
        if (cc < 3) {
            char* wbase = (char*)&e_s[buf ^ 1][0];
            *reinterpret_cast<bf16x8*>(wbase + wb0) = pack8(a0, a1);
            *reinterpret_cast<bf16x8*>(wbase + wb1) = pack8(a2, a3);
        }
        __syncthreads();
    }

    // ---- epilogue: scores for this wave's head, 64 local j ----
    const float* Kb  = Kw + (size_t)b * NNODE * HD;
    const float* krw = k_RW + (size_t)bi * NNODE + j0;
    float q_l[4], be_l[4];
#pragma unroll
    for (int dc = 0; dc < 4; ++dc) {
        q_l[dc]  = Qw[(size_t)bi * HD + h * 64 + dc * 16 + c15];
        be_l[dc] = be[h * 64 + dc * 16 + c15];
    }

#pragma unroll
    for (int jm = 0; jm < 4; ++jm) {
#pragma unroll
        for (int r = 0; r < 4; ++r) {
            int jl = jm * 16 + g * 4 + r;       // local j within half
            float sacc = 0.f;
#pragma unroll
            for (int dc = 0; dc < 4; ++dc) {
                float ev = acc[jm][dc][r] + be_l[dc];
                float kv = Kb[(size_t)(j0 + jl) * HD + h * 64 + dc * 16 + c15];
                sacc += ev * q_l[dc] * kv;
            }
            sacc += __shfl_xor(sacc, 1);
            sacc += __shfl_xor(sacc, 2);
            sacc += __shfl_xor(sacc, 4);
            sacc += __shfl_xor(sacc, 8);
            if (c15 == 0) {
                float sv = fminf(fmaxf(sacc, -5.f), 5.f);
                s_lds[h][jl] = __expf(sv) * krw[jl];
            }
        }
    }
    __syncthreads();

    // ---- PV partials: wave h, lane = d ----
    const float* Vb = Vw + (size_t)b * NNODE * HD;
    float o = 0.f, den = 0.f;
#pragma unroll 4
    for (int jl = 0; jl < 64; ++jl) {
        float sv = s_lds[h][jl];
        o = fmaf(sv, Vb[(size_t)(j0 + jl) * HD + h * 64 + l], o);
        den += sv;
    }
    PN[((size_t)bx * 8 + h) * 64 + l] = o;
    if (l == 0) PD[(size_t)bx * 8 + h] = den;
}

// ---------------------------------------------------------------------------
// Kernel 4: combine the two j-half partials and normalize.
// ---------------------------------------------------------------------------
__global__ __launch_bounds__(512) void k_norm(
    const float* __restrict__ PN, const float* __restrict__ PD,
    float* __restrict__ out)
{
    const int bi = blockIdx.x;
    const int t  = threadIdx.x;
    const int h  = t >> 6;
    const int d  = t & 63;
    size_t r0 = ((size_t)(bi * 2 + 0) * 8 + h);
    size_t r1 = ((size_t)(bi * 2 + 1) * 8 + h);
    float num = PN[r0 * 64 + d] + PN[r1 * 64 + d];
    float den = fmaxf(PD[r0] + PD[r1], 1e-6f);
    out[(size_t)bi * HD + h * 64 + d] = num / den;
}

// ---------------------------------------------------------------------------
extern "C" void kernel_launch(void* const* d_in, const int* in_sizes, int n_in,
                              void* d_out, int out_size, void* d_ws, size_t ws_size,
                              hipStream_t stream) {
    const float* hin = (const float*)d_in[0];
    const float* e   = (const float*)d_in[1];
    const float* krw = (const float*)d_in[2];
    const float* Wq  = (const float*)d_in[3];
    const float* bq  = (const float*)d_in[4];
    const float* Wk  = (const float*)d_in[5];
    const float* bk  = (const float*)d_in[6];
    const float* We  = (const float*)d_in[7];
    const float* be  = (const float*)d_in[8];
    const float* Wv  = (const float*)d_in[9];
    const float* bv  = (const float*)d_in[10];
    float* out = (float*)d_out;

    char* ws = (char*)d_ws;
    unsigned short* WT  = (unsigned short*)ws;                // 2 MB (slices 1..3 used)
    float* Q  = (float*)(ws + (2ull << 20));                  // 2 MB
    float* K  = (float*)(ws + (4ull << 20));                  // 2 MB
    float* V  = (float*)(ws + (6ull << 20));                  // 2 MB
    float* PN = (float*)(ws + (8ull << 20));                  // 4 MB
    float* PD = (float*)(ws + (12ull << 20));                 // 64 KB
    unsigned short* WT2 = (unsigned short*)(ws + (13ull << 20)); // 512 KB

    k_wt <<<dim3(8, 8, 3), dim3(256), 0, stream>>>(Wq, Wk, Wv, WT);
    k_wt2<<<dim3(8, 4),    dim3(256), 0, stream>>>(We, WT2);
    k_qkv<<<dim3(16, 8, 3), dim3(256), 0, stream>>>(hin, WT, bq, bk, bv, Q, K, V);
    k_main<<<dim3(2048), dim3(512), 0, stream>>>(e, krw, WT2, be, Q, K, V, PN, PD);
    k_norm<<<dim3(1024), dim3(512), 0, stream>>>(PN, PD, out);
}